// Round 4
// baseline (1969.388 us; speedup 1.0000x reference)
//
#include <hip/hip_runtime.h>
#include <math.h>

constexpr int DH  = 256;
constexpr int DZ  = 128;
constexpr float EPS   = 1e-5f;
constexpr float SLOPE = 0.01f;

typedef __attribute__((ext_vector_type(8))) short bf16x8;
typedef __attribute__((ext_vector_type(4))) float f32x4;

__device__ __forceinline__ short f2bf(float f) {
    union { float f; unsigned u; } v; v.f = f;
    unsigned r = v.u + 0x7fffu + ((v.u >> 16) & 1u);   // RNE
    return (short)(r >> 16);
}
__device__ __forceinline__ float bf2f(short s) {
    union { unsigned u; float f; } v;
    v.u = ((unsigned)(unsigned short)s) << 16;
    return v.f;
}
__device__ __forceinline__ unsigned cvt_pk_bf16(float lo, float hi) {
    unsigned r;
    asm volatile("v_cvt_pk_bf16_f32 %0, %1, %2" : "=v"(r) : "v"(lo), "v"(hi));
    return r;
}

// ---------------------------------------------------------------------------
// degree (int) / dinv
// ---------------------------------------------------------------------------
__global__ void deg_count_i(const int* __restrict__ dst, int* __restrict__ deg, int E) {
    int e = blockIdx.x * blockDim.x + threadIdx.x;
    if (e < E) atomicAdd(&deg[dst[e]], 1);
}

__global__ void make_dinv(const int* __restrict__ deg, float* __restrict__ dinv, int N) {
    int i = blockIdx.x * blockDim.x + threadIdx.x;
    if (i < N) dinv[i] = rsqrtf((float)deg[i] + 1.0f);
}

// ---------------------------------------------------------------------------
// exclusive scan of deg[N] -> rowptr
// ---------------------------------------------------------------------------
__global__ __launch_bounds__(256)
void scan1(const int* __restrict__ deg, int* __restrict__ rowptr,
           int* __restrict__ blocksum, int N) {
    __shared__ int ts[256];
    int base = blockIdx.x * 1024 + threadIdx.x * 4;
    int v[4], s = 0;
#pragma unroll
    for (int i = 0; i < 4; ++i) {
        v[i] = (base + i < N) ? deg[base + i] : 0;
        s += v[i];
    }
    ts[threadIdx.x] = s;
    __syncthreads();
    for (int off = 1; off < 256; off <<= 1) {
        int t = 0;
        if ((int)threadIdx.x >= off) t = ts[threadIdx.x - off];
        __syncthreads();
        if ((int)threadIdx.x >= off) ts[threadIdx.x] += t;
        __syncthreads();
    }
    int run = ts[threadIdx.x] - s;
#pragma unroll
    for (int i = 0; i < 4; ++i) {
        if (base + i < N) rowptr[base + i] = run;
        run += v[i];
    }
    if (threadIdx.x == 255) blocksum[blockIdx.x] = ts[255];
}

__global__ __launch_bounds__(256)
void scan2(const int* __restrict__ blocksum, int* __restrict__ blockoff,
           int nb, int* __restrict__ rowptr_last) {
    __shared__ int ts[256];
    int v = ((int)threadIdx.x < nb) ? blocksum[threadIdx.x] : 0;
    ts[threadIdx.x] = v;
    __syncthreads();
    for (int off = 1; off < 256; off <<= 1) {
        int t = 0;
        if ((int)threadIdx.x >= off) t = ts[threadIdx.x - off];
        __syncthreads();
        if ((int)threadIdx.x >= off) ts[threadIdx.x] += t;
        __syncthreads();
    }
    blockoff[threadIdx.x] = ts[threadIdx.x] - v;
    if (threadIdx.x == 255) *rowptr_last = ts[255];
}

__global__ void scan3(int* __restrict__ rowptr, const int* __restrict__ blockoff, int N) {
    int i = blockIdx.x * blockDim.x + threadIdx.x;
    if (i < N) rowptr[i] += blockoff[i >> 10];
}

// csr_fill precomputes per-edge weight dinv[src]*dinv[dst]; stores {src, w}.
__global__ void csr_fill(const int* __restrict__ src, const int* __restrict__ dst,
                         const int* __restrict__ rowptr, int* __restrict__ fill,
                         int2* __restrict__ csr_iw, const float* __restrict__ dinv,
                         int E) {
    int e = blockIdx.x * blockDim.x + threadIdx.x;
    if (e >= E) return;
    int d = dst[e];
    int s = src[e];
    int pos = rowptr[d] + atomicAdd(&fill[d], 1);
    float w = dinv[d] * dinv[s];
    csr_iw[pos] = make_int2(s, __float_as_int(w));
}

// ---------------------------------------------------------------------------
// casts
// ---------------------------------------------------------------------------
__global__ void cast_bf16(const float* __restrict__ x, short* __restrict__ y, int n4) {
    int i = blockIdx.x * blockDim.x + threadIdx.x;
    if (i >= n4) return;
    float4 v = ((const float4*)x)[i];
    short4 o;
    o.x = f2bf(v.x); o.y = f2bf(v.y); o.z = f2bf(v.z); o.w = f2bf(v.w);
    ((short4*)y)[i] = o;
}

__global__ void wt_cast(const float* __restrict__ W, short* __restrict__ Wt, int K, int NC) {
    int idx = blockIdx.x * blockDim.x + threadIdx.x;
    if (idx >= K * NC) return;
    int n = idx / K, k = idx % K;
    Wt[idx] = f2bf(W[k * NC + n]);
}

// ---------------------------------------------------------------------------
// bf16 MFMA GEMM (plain A): C[M,NC](bf16) = A[M,K] @ Wt[NC,K]^T, double-buffered
// ---------------------------------------------------------------------------
__global__ __launch_bounds__(256)
void gemm_mfma(const short* __restrict__ A, const short* __restrict__ Bt,
               short* __restrict__ C, int M, int K, int NC) {
    __shared__ short As[2][128 * 32];
    __shared__ short Bs[2][128 * 32];
    const int tid  = threadIdx.x;
    const int lane = tid & 63;
    const int w    = tid >> 6;
    const int wm   = w & 1, wn = w >> 1;
    const int bm   = blockIdx.x * 128;
    const int bn   = blockIdx.y * 128;

    const int srow = w * 16 + (lane >> 2);
    const int scol = (lane & 3) * 8;

    const int ga_r0 = (bm + srow      < M) ? bm + srow      : M - 1;
    const int ga_r1 = (bm + srow + 64 < M) ? bm + srow + 64 : M - 1;
    const size_t arow0 = (size_t)ga_r0 * K;
    const size_t arow1 = (size_t)ga_r1 * K;
    const size_t brow0 = (size_t)(bn + srow) * K;
    const size_t brow1 = (size_t)(bn + srow + 64) * K;

    auto stage = [&](int buf, int k0) {
        __builtin_amdgcn_global_load_lds(
            (const __attribute__((address_space(1))) void*)(A + arow0 + k0 + scol),
            (__attribute__((address_space(3))) void*)&As[buf][srow * 32 + scol], 16, 0, 0);
        __builtin_amdgcn_global_load_lds(
            (const __attribute__((address_space(1))) void*)(A + arow1 + k0 + scol),
            (__attribute__((address_space(3))) void*)&As[buf][(srow + 64) * 32 + scol], 16, 0, 0);
        __builtin_amdgcn_global_load_lds(
            (const __attribute__((address_space(1))) void*)(Bt + brow0 + k0 + scol),
            (__attribute__((address_space(3))) void*)&Bs[buf][srow * 32 + scol], 16, 0, 0);
        __builtin_amdgcn_global_load_lds(
            (const __attribute__((address_space(1))) void*)(Bt + brow1 + k0 + scol),
            (__attribute__((address_space(3))) void*)&Bs[buf][(srow + 64) * 32 + scol], 16, 0, 0);
    };

    f32x4 acc[4][4];
#pragma unroll
    for (int i = 0; i < 4; ++i)
#pragma unroll
        for (int j = 0; j < 4; ++j) acc[i][j] = (f32x4){0.f, 0.f, 0.f, 0.f};

    const int frow = lane & 15;
    const int kg   = (lane >> 4) * 8;
    const int nk   = K >> 5;

    stage(0, 0);
    __syncthreads();

    for (int kk = 0; kk < nk; ++kk) {
        const int cur = kk & 1;
        if (kk + 1 < nk) stage(cur ^ 1, (kk + 1) << 5);

        bf16x8 af[4], bfr[4];
#pragma unroll
        for (int i = 0; i < 4; ++i)
            af[i] = *(const bf16x8*)&As[cur][(wm * 64 + i * 16 + frow) * 32 + kg];
#pragma unroll
        for (int j = 0; j < 4; ++j)
            bfr[j] = *(const bf16x8*)&Bs[cur][(wn * 64 + j * 16 + frow) * 32 + kg];
#pragma unroll
        for (int i = 0; i < 4; ++i)
#pragma unroll
            for (int j = 0; j < 4; ++j)
                acc[i][j] = __builtin_amdgcn_mfma_f32_16x16x32_bf16(
                    af[i], bfr[j], acc[i][j], 0, 0, 0);

        __syncthreads();
    }

    const int row_base = bm + wm * 64 + (lane >> 4) * 4;
    const int col_base = bn + wn * 64 + (lane & 15);
#pragma unroll
    for (int i = 0; i < 4; ++i) {
#pragma unroll
        for (int r = 0; r < 4; ++r) {
            int row = row_base + i * 16 + r;
            if (row < M) {
                short* cp = C + (size_t)row * NC + col_base;
#pragma unroll
                for (int j = 0; j < 4; ++j) cp[j * 16] = f2bf(acc[i][j][r]);
            }
        }
    }
}

// ---------------------------------------------------------------------------
// GEMM with fused LN+leakyReLU on A: A' = leaky(A*s[c] + t[c]), st = {s[256],t[256]}.
// A staged via registers (load bf16x8 -> fma -> max -> cvt_pk -> ds_write_b128);
// B stays on global_load_lds. Deletes the standalone ln_apply pass.
// ---------------------------------------------------------------------------
__global__ __launch_bounds__(256)
void gemm_mfma_ln(const short* __restrict__ A, const short* __restrict__ Bt,
                  short* __restrict__ C, const float* __restrict__ st,
                  int M, int K, int NC) {
    __shared__ short As[2][128 * 32];
    __shared__ short Bs[2][128 * 32];
    const int tid  = threadIdx.x;
    const int lane = tid & 63;
    const int w    = tid >> 6;
    const int wm   = w & 1, wn = w >> 1;
    const int bm   = blockIdx.x * 128;
    const int bn   = blockIdx.y * 128;

    const int srow = w * 16 + (lane >> 2);
    const int scol = (lane & 3) * 8;

    const int ga_r0 = (bm + srow      < M) ? bm + srow      : M - 1;
    const int ga_r1 = (bm + srow + 64 < M) ? bm + srow + 64 : M - 1;
    const size_t arow0 = (size_t)ga_r0 * K;
    const size_t arow1 = (size_t)ga_r1 * K;
    const size_t brow0 = (size_t)(bn + srow) * K;
    const size_t brow1 = (size_t)(bn + srow + 64) * K;

    auto stageB = [&](int buf, int k0) {
        __builtin_amdgcn_global_load_lds(
            (const __attribute__((address_space(1))) void*)(Bt + brow0 + k0 + scol),
            (__attribute__((address_space(3))) void*)&Bs[buf][srow * 32 + scol], 16, 0, 0);
        __builtin_amdgcn_global_load_lds(
            (const __attribute__((address_space(1))) void*)(Bt + brow1 + k0 + scol),
            (__attribute__((address_space(3))) void*)&Bs[buf][(srow + 64) * 32 + scol], 16, 0, 0);
    };

    auto stA = [&](int buf, int k0, bf16x8 a0, bf16x8 a1) {
        const float* sp = st + k0 + scol;
        const float* tp = st + 256 + k0 + scol;
        float4 s0 = *(const float4*)sp,       s1 = *(const float4*)(sp + 4);
        float4 t0 = *(const float4*)tp,       t1 = *(const float4*)(tp + 4);
        float sv[8] = {s0.x, s0.y, s0.z, s0.w, s1.x, s1.y, s1.z, s1.w};
        float tv[8] = {t0.x, t0.y, t0.z, t0.w, t1.x, t1.y, t1.z, t1.w};
        unsigned p0[4], p1[4];
#pragma unroll
        for (int q = 0; q < 4; ++q) {
            float x0 = fmaf(bf2f(a0[2*q]),     sv[2*q],     tv[2*q]);
            float x1 = fmaf(bf2f(a0[2*q + 1]), sv[2*q + 1], tv[2*q + 1]);
            x0 = fmaxf(x0, x0 * SLOPE);
            x1 = fmaxf(x1, x1 * SLOPE);
            p0[q] = cvt_pk_bf16(x0, x1);
            float y0 = fmaf(bf2f(a1[2*q]),     sv[2*q],     tv[2*q]);
            float y1 = fmaf(bf2f(a1[2*q + 1]), sv[2*q + 1], tv[2*q + 1]);
            y0 = fmaxf(y0, y0 * SLOPE);
            y1 = fmaxf(y1, y1 * SLOPE);
            p1[q] = cvt_pk_bf16(y0, y1);
        }
        *(int4*)&As[buf][srow * 32 + scol]        = make_int4(p0[0], p0[1], p0[2], p0[3]);
        *(int4*)&As[buf][(srow + 64) * 32 + scol] = make_int4(p1[0], p1[1], p1[2], p1[3]);
    };

    f32x4 acc[4][4];
#pragma unroll
    for (int i = 0; i < 4; ++i)
#pragma unroll
        for (int j = 0; j < 4; ++j) acc[i][j] = (f32x4){0.f, 0.f, 0.f, 0.f};

    const int frow = lane & 15;
    const int kg   = (lane >> 4) * 8;
    const int nk   = K >> 5;

    {
        bf16x8 a0 = *(const bf16x8*)(A + arow0 + scol);
        bf16x8 a1 = *(const bf16x8*)(A + arow1 + scol);
        stageB(0, 0);
        stA(0, 0, a0, a1);
    }
    __syncthreads();

    for (int kk = 0; kk < nk; ++kk) {
        const int cur = kk & 1;
        const bool pre = (kk + 1 < nk);
        bf16x8 a0, a1;
        if (pre) {
            const int k1 = (kk + 1) << 5;
            a0 = *(const bf16x8*)(A + arow0 + k1 + scol);   // issued early
            a1 = *(const bf16x8*)(A + arow1 + k1 + scol);
            stageB(cur ^ 1, k1);
        }

        bf16x8 af[4], bfr[4];
#pragma unroll
        for (int i = 0; i < 4; ++i)
            af[i] = *(const bf16x8*)&As[cur][(wm * 64 + i * 16 + frow) * 32 + kg];
#pragma unroll
        for (int j = 0; j < 4; ++j)
            bfr[j] = *(const bf16x8*)&Bs[cur][(wn * 64 + j * 16 + frow) * 32 + kg];
#pragma unroll
        for (int i = 0; i < 4; ++i)
#pragma unroll
            for (int j = 0; j < 4; ++j)
                acc[i][j] = __builtin_amdgcn_mfma_f32_16x16x32_bf16(
                    af[i], bfr[j], acc[i][j], 0, 0, 0);

        if (pre) stA(cur ^ 1, (kk + 1) << 5, a0, a1);   // write-late
        __syncthreads();
    }

    const int row_base = bm + wm * 64 + (lane >> 4) * 4;
    const int col_base = bn + wn * 64 + (lane & 15);
#pragma unroll
    for (int i = 0; i < 4; ++i) {
#pragma unroll
        for (int r = 0; r < 4; ++r) {
            int row = row_base + i * 16 + r;
            if (row < M) {
                short* cp = C + (size_t)row * NC + col_base;
#pragma unroll
                for (int j = 0; j < 4; ++j) cp[j * 16] = f2bf(acc[i][j][r]);
            }
        }
    }
}

// ---------------------------------------------------------------------------
// CSR aggregation (bf16 gather, fp32 acc) + fused LN stats; R1's proven
// 4-deep unroll. Last-done block reduces the partials and writes the
// per-channel LN coefficients s[c]=inv*g[c], t[c]=be[c]-mu*inv*g[c].
// ---------------------------------------------------------------------------
__global__ __launch_bounds__(256)
void agg_ln_csr(const short* __restrict__ h, const int* __restrict__ rowptr,
                const int2* __restrict__ csr_iw, const float* __restrict__ dinv,
                const float* __restrict__ bias, short* __restrict__ agg,
                float* __restrict__ psum, float* __restrict__ psumsq,
                const float* __restrict__ gamma, const float* __restrict__ beta,
                float* __restrict__ st, int* __restrict__ cnt, int N, int nbk) {
    constexpr int TPN = 32;                 // D=256 bf16 -> 32 x 16B
    int t = blockIdx.x * 256 + threadIdx.x;
    int n = t / TPN, l = t % TPN;
    float acc[8] = {0.f, 0.f, 0.f, 0.f, 0.f, 0.f, 0.f, 0.f};
    if (n < N) {
        const bf16x8* h8 = (const bf16x8*)h;   // row = 32 vectors
        float di = dinv[n];
        float sl2 = di * di;
        bf16x8 sv = h8[(size_t)n * TPN + l];
        const float* bp = bias + l * 8;
#pragma unroll
        for (int c = 0; c < 8; ++c) acc[c] = bf2f(sv[c]) * sl2 + bp[c];
        int j = rowptr[n], j1 = rowptr[n + 1];
        for (; j + 3 < j1; j += 4) {
            int2 e0 = csr_iw[j],     e1 = csr_iw[j + 1];
            int2 e2 = csr_iw[j + 2], e3 = csr_iw[j + 3];
            float w0 = __int_as_float(e0.y), w1 = __int_as_float(e1.y);
            float w2 = __int_as_float(e2.y), w3 = __int_as_float(e3.y);
            bf16x8 v0 = h8[(size_t)e0.x * TPN + l];
            bf16x8 v1 = h8[(size_t)e1.x * TPN + l];
            bf16x8 v2 = h8[(size_t)e2.x * TPN + l];
            bf16x8 v3 = h8[(size_t)e3.x * TPN + l];
#pragma unroll
            for (int c = 0; c < 8; ++c)
                acc[c] += bf2f(v0[c]) * w0 + bf2f(v1[c]) * w1 +
                          bf2f(v2[c]) * w2 + bf2f(v3[c]) * w3;
        }
        if (j + 1 < j1) {
            int2 e0 = csr_iw[j], e1 = csr_iw[j + 1];
            float w0 = __int_as_float(e0.y), w1 = __int_as_float(e1.y);
            bf16x8 v0 = h8[(size_t)e0.x * TPN + l];
            bf16x8 v1 = h8[(size_t)e1.x * TPN + l];
#pragma unroll
            for (int c = 0; c < 8; ++c)
                acc[c] += bf2f(v0[c]) * w0 + bf2f(v1[c]) * w1;
            j += 2;
        }
        if (j < j1) {
            int2 e0 = csr_iw[j];
            float w0 = __int_as_float(e0.y);
            bf16x8 v0 = h8[(size_t)e0.x * TPN + l];
#pragma unroll
            for (int c = 0; c < 8; ++c) acc[c] += bf2f(v0[c]) * w0;
        }
        bf16x8 o;
#pragma unroll
        for (int c = 0; c < 8; ++c) o[c] = f2bf(acc[c]);
        ((bf16x8*)agg)[(size_t)n * TPN + l] = o;
    }
    // LN partial stats -> per-block array (contention-free)
    float s = 0.f, q = 0.f;
#pragma unroll
    for (int c = 0; c < 8; ++c) { s += acc[c]; q += acc[c] * acc[c]; }
#pragma unroll
    for (int off = 32; off; off >>= 1) {
        s += __shfl_down(s, off);
        q += __shfl_down(q, off);
    }
    __shared__ float ss[4], qq[4];
    __shared__ int lastFlag;
    int wid = threadIdx.x >> 6, lane = threadIdx.x & 63;
    if (lane == 0) { ss[wid] = s; qq[wid] = q; }
    __syncthreads();
    if (threadIdx.x == 0) {
        psum[blockIdx.x]   = ss[0] + ss[1] + ss[2] + ss[3];
        psumsq[blockIdx.x] = qq[0] + qq[1] + qq[2] + qq[3];
        __threadfence();
        lastFlag = (atomicAdd(cnt, 1) == (int)gridDim.x - 1);
    }
    __syncthreads();
    if (lastFlag) {
        __threadfence();
        double ds_ = 0.0, dq_ = 0.0;
        for (int i = threadIdx.x; i < nbk; i += 256) {
            ds_ += (double)psum[i];
            dq_ += (double)psumsq[i];
        }
#pragma unroll
        for (int off = 32; off; off >>= 1) {
            ds_ += __shfl_down(ds_, off);
            dq_ += __shfl_down(dq_, off);
        }
        __shared__ double rs[4], rq[4];
        __shared__ float mi[2];
        if (lane == 0) { rs[wid] = ds_; rq[wid] = dq_; }
        __syncthreads();
        if (threadIdx.x == 0) {
            double S = rs[0] + rs[1] + rs[2] + rs[3];
            double Q = rq[0] + rq[1] + rq[2] + rq[3];
            double M = (double)N * (double)DH;
            double mu  = S / M;
            double var = Q / M - mu * mu;
            if (var < 0.0) var = 0.0;
            mi[0] = (float)mu;
            mi[1] = 1.0f / ((float)sqrt(var) + EPS);
        }
        __syncthreads();
        float mu = mi[0], inv = mi[1];
        int c = threadIdx.x;                 // 256 threads == DH channels
        float gv = gamma[c], bv = beta[c];
        st[c]       = inv * gv;
        st[256 + c] = bv - mu * inv * gv;
    }
}

// final layer: D=128, 16 lanes/node (16B), 4 nodes/wave, fp32 out, no stats
__global__ __launch_bounds__(256)
void agg_out_csr(const short* __restrict__ h, const int* __restrict__ rowptr,
                 const int2* __restrict__ csr_iw, const float* __restrict__ dinv,
                 const float* __restrict__ bias, float* __restrict__ out, int N) {
    constexpr int TPN = 16;                 // D=128 bf16 -> 16 x 16B
    int t = blockIdx.x * 256 + threadIdx.x;
    int n = t / TPN, l = t % TPN;
    if (n >= N) return;
    const bf16x8* h8 = (const bf16x8*)h;
    float di = dinv[n];
    float sl2 = di * di;
    bf16x8 sv = h8[(size_t)n * TPN + l];
    const float* bp = bias + l * 8;
    float acc[8];
#pragma unroll
    for (int c = 0; c < 8; ++c) acc[c] = bf2f(sv[c]) * sl2 + bp[c];
    int j = rowptr[n], j1 = rowptr[n + 1];
    for (; j + 3 < j1; j += 4) {
        int2 e0 = csr_iw[j],     e1 = csr_iw[j + 1];
        int2 e2 = csr_iw[j + 2], e3 = csr_iw[j + 3];
        float w0 = __int_as_float(e0.y), w1 = __int_as_float(e1.y);
        float w2 = __int_as_float(e2.y), w3 = __int_as_float(e3.y);
        bf16x8 v0 = h8[(size_t)e0.x * TPN + l];
        bf16x8 v1 = h8[(size_t)e1.x * TPN + l];
        bf16x8 v2 = h8[(size_t)e2.x * TPN + l];
        bf16x8 v3 = h8[(size_t)e3.x * TPN + l];
#pragma unroll
        for (int c = 0; c < 8; ++c)
            acc[c] += bf2f(v0[c]) * w0 + bf2f(v1[c]) * w1 +
                      bf2f(v2[c]) * w2 + bf2f(v3[c]) * w3;
    }
    if (j + 1 < j1) {
        int2 e0 = csr_iw[j], e1 = csr_iw[j + 1];
        float w0 = __int_as_float(e0.y), w1 = __int_as_float(e1.y);
        bf16x8 v0 = h8[(size_t)e0.x * TPN + l];
        bf16x8 v1 = h8[(size_t)e1.x * TPN + l];
#pragma unroll
        for (int c = 0; c < 8; ++c)
            acc[c] += bf2f(v0[c]) * w0 + bf2f(v1[c]) * w1;
        j += 2;
    }
    if (j < j1) {
        int2 e0 = csr_iw[j];
        float w0 = __int_as_float(e0.y);
        bf16x8 v0 = h8[(size_t)e0.x * TPN + l];
#pragma unroll
        for (int c = 0; c < 8; ++c) acc[c] += bf2f(v0[c]) * w0;
    }
    float4* op = (float4*)(out + (size_t)n * 128 + l * 8);
    op[0] = make_float4(acc[0], acc[1], acc[2], acc[3]);
    op[1] = make_float4(acc[4], acc[5], acc[6], acc[7]);
}

// ---------------------------------------------------------------------------
// launcher
// ---------------------------------------------------------------------------
extern "C" void kernel_launch(void* const* d_in, const int* in_sizes, int n_in,
                              void* d_out, int out_size, void* d_ws, size_t ws_size,
                              hipStream_t stream) {
    const float* x   = (const float*)d_in[0];
    const int*   ei  = (const int*)d_in[1];
    const float* W1  = (const float*)d_in[2];
    const float* b1  = (const float*)d_in[3];
    const float* g1  = (const float*)d_in[4];
    const float* be1 = (const float*)d_in[5];
    const float* W2  = (const float*)d_in[6];
    const float* b2  = (const float*)d_in[7];
    const float* g2  = (const float*)d_in[8];
    const float* be2 = (const float*)d_in[9];
    const float* W3  = (const float*)d_in[10];
    const float* b3  = (const float*)d_in[11];
    const float* g3  = (const float*)d_in[12];
    const float* be3 = (const float*)d_in[13];
    const float* W4  = (const float*)d_in[14];
    const float* b4  = (const float*)d_in[15];

    const int N = in_sizes[0] / DH;   // 100000
    const int E = in_sizes[1] / 2;    // 800000
    const int* src = ei;
    const int* dst = ei + E;
    const int nb = (N + 1023) / 1024;
    const int nagg = (N * 32 + 255) / 256;   // agg_ln_csr blocks (12500)

    char* w = (char*)d_ws;
    size_t off = 0;
    auto alloc = [&](size_t bytes) { char* p = w + off; off = (off + bytes + 255) & ~(size_t)255; return p; };
    int*    deg      = (int*)alloc((size_t)N * 4);
    int*    fill     = (int*)alloc((size_t)N * 4);
    int*    cnt      = (int*)alloc(64);
    int*    rowptr   = (int*)alloc((size_t)(N + 1) * 4);
    int*    blocksum = (int*)alloc(256 * 4);
    int*    blockoff = (int*)alloc(256 * 4);
    float*  dinv     = (float*)alloc((size_t)N * 4);
    float*  psum     = (float*)alloc((size_t)nagg * 4);
    float*  psumsq   = (float*)alloc((size_t)nagg * 4);
    float*  st1      = (float*)alloc(512 * 4);
    float*  st2      = (float*)alloc(512 * 4);
    float*  st3      = (float*)alloc(512 * 4);
    int2*   csr_iw   = (int2*)alloc((size_t)E * 8);
    short*  Wt1      = (short*)alloc((size_t)DH * DH * 2);
    short*  Wt2      = (short*)alloc((size_t)DH * DH * 2);
    short*  Wt3      = (short*)alloc((size_t)DH * DH * 2);
    short*  Wt4      = (short*)alloc((size_t)DZ * DH * 2);
    short*  actbf    = (short*)alloc((size_t)N * DH * 2);
    short*  hbf      = (short*)alloc((size_t)N * DH * 2);
    short*  aggb     = (short*)alloc((size_t)N * DH * 2);

    // ---- one memset for deg + fill + cnt (contiguous) ----
    hipMemsetAsync(deg, 0, (size_t)((char*)cnt + 64 - (char*)deg), stream);

    // ---- degree, dinv, CSR build ----
    deg_count_i<<<(E + 255) / 256, 256, 0, stream>>>(dst, deg, E);
    make_dinv<<<(N + 255) / 256, 256, 0, stream>>>(deg, dinv, N);
    scan1<<<nb, 256, 0, stream>>>(deg, rowptr, blocksum, N);
    scan2<<<1, 256, 0, stream>>>(blocksum, blockoff, nb, rowptr + N);
    scan3<<<(N + 255) / 256, 256, 0, stream>>>(rowptr, blockoff, N);
    csr_fill<<<(E + 255) / 256, 256, 0, stream>>>(src, dst, rowptr, fill, csr_iw, dinv, E);

    // ---- weight transpose+cast, input cast ----
    wt_cast<<<(DH * DH + 255) / 256, 256, 0, stream>>>(W1, Wt1, DH, DH);
    wt_cast<<<(DH * DH + 255) / 256, 256, 0, stream>>>(W2, Wt2, DH, DH);
    wt_cast<<<(DH * DH + 255) / 256, 256, 0, stream>>>(W3, Wt3, DH, DH);
    wt_cast<<<(DH * DZ + 255) / 256, 256, 0, stream>>>(W4, Wt4, DH, DZ);
    cast_bf16<<<(N * DH / 4 + 255) / 256, 256, 0, stream>>>(x, actbf, N * DH / 4);

    const int gmM = (N + 127) / 128;

    // layer 1: plain gemm on cast(x), agg writes st1
    gemm_mfma<<<dim3(gmM, DH / 128), 256, 0, stream>>>(actbf, Wt1, hbf, N, DH, DH);
    agg_ln_csr<<<nagg, 256, 0, stream>>>(hbf, rowptr, csr_iw, dinv, b1, aggb,
                                         psum, psumsq, g1, be1, st1, cnt + 0, N, nagg);
    // layer 2: LN1+leaky fused into gemm A-staging
    gemm_mfma_ln<<<dim3(gmM, DH / 128), 256, 0, stream>>>(aggb, Wt2, hbf, st1, N, DH, DH);
    agg_ln_csr<<<nagg, 256, 0, stream>>>(hbf, rowptr, csr_iw, dinv, b2, aggb,
                                         psum, psumsq, g2, be2, st2, cnt + 1, N, nagg);
    // layer 3
    gemm_mfma_ln<<<dim3(gmM, DH / 128), 256, 0, stream>>>(aggb, Wt3, hbf, st2, N, DH, DH);
    agg_ln_csr<<<nagg, 256, 0, stream>>>(hbf, rowptr, csr_iw, dinv, b3, aggb,
                                         psum, psumsq, g3, be3, st3, cnt + 2, N, nagg);
    // final conv: LN3+leaky fused, DH -> DZ
    gemm_mfma_ln<<<dim3(gmM, DZ / 128), 256, 0, stream>>>(aggb, Wt4, hbf, st3, N, DH, DZ);
    float* out = (float*)d_out;
    int naggz = (N * 16 + 255) / 256;
    agg_out_csr<<<naggz, 256, 0, stream>>>(hbf, rowptr, csr_iw, dinv, b4, out, N);
}

// Round 5
// 683.460 us; speedup vs baseline: 2.8815x; 2.8815x over previous
//
#include <hip/hip_runtime.h>
#include <math.h>

constexpr int DH  = 256;
constexpr int DZ  = 128;
constexpr float EPS   = 1e-5f;
constexpr float SLOPE = 0.01f;

typedef __attribute__((ext_vector_type(8))) short bf16x8;
typedef __attribute__((ext_vector_type(4))) float f32x4;

__device__ __forceinline__ short f2bf(float f) {
    union { float f; unsigned u; } v; v.f = f;
    unsigned r = v.u + 0x7fffu + ((v.u >> 16) & 1u);   // RNE
    return (short)(r >> 16);
}
__device__ __forceinline__ float bf2f(short s) {
    union { unsigned u; float f; } v;
    v.u = ((unsigned)(unsigned short)s) << 16;
    return v.f;
}
__device__ __forceinline__ unsigned cvt_pk_bf16(float lo, float hi) {
    unsigned r;
    asm volatile("v_cvt_pk_bf16_f32 %0, %1, %2" : "=v"(r) : "v"(lo), "v"(hi));
    return r;
}

// ---------------------------------------------------------------------------
// degree (int) / dinv
// ---------------------------------------------------------------------------
__global__ void deg_count_i(const int* __restrict__ dst, int* __restrict__ deg, int E) {
    int e = blockIdx.x * blockDim.x + threadIdx.x;
    if (e < E) atomicAdd(&deg[dst[e]], 1);
}

__global__ void make_dinv(const int* __restrict__ deg, float* __restrict__ dinv, int N) {
    int i = blockIdx.x * blockDim.x + threadIdx.x;
    if (i < N) dinv[i] = rsqrtf((float)deg[i] + 1.0f);
}

// ---------------------------------------------------------------------------
// exclusive scan of deg[N] -> rowptr
// ---------------------------------------------------------------------------
__global__ __launch_bounds__(256)
void scan1(const int* __restrict__ deg, int* __restrict__ rowptr,
           int* __restrict__ blocksum, int N) {
    __shared__ int ts[256];
    int base = blockIdx.x * 1024 + threadIdx.x * 4;
    int v[4], s = 0;
#pragma unroll
    for (int i = 0; i < 4; ++i) {
        v[i] = (base + i < N) ? deg[base + i] : 0;
        s += v[i];
    }
    ts[threadIdx.x] = s;
    __syncthreads();
    for (int off = 1; off < 256; off <<= 1) {
        int t = 0;
        if ((int)threadIdx.x >= off) t = ts[threadIdx.x - off];
        __syncthreads();
        if ((int)threadIdx.x >= off) ts[threadIdx.x] += t;
        __syncthreads();
    }
    int run = ts[threadIdx.x] - s;
#pragma unroll
    for (int i = 0; i < 4; ++i) {
        if (base + i < N) rowptr[base + i] = run;
        run += v[i];
    }
    if (threadIdx.x == 255) blocksum[blockIdx.x] = ts[255];
}

__global__ __launch_bounds__(256)
void scan2(const int* __restrict__ blocksum, int* __restrict__ blockoff,
           int nb, int* __restrict__ rowptr_last) {
    __shared__ int ts[256];
    int v = ((int)threadIdx.x < nb) ? blocksum[threadIdx.x] : 0;
    ts[threadIdx.x] = v;
    __syncthreads();
    for (int off = 1; off < 256; off <<= 1) {
        int t = 0;
        if ((int)threadIdx.x >= off) t = ts[threadIdx.x - off];
        __syncthreads();
        if ((int)threadIdx.x >= off) ts[threadIdx.x] += t;
        __syncthreads();
    }
    blockoff[threadIdx.x] = ts[threadIdx.x] - v;
    if (threadIdx.x == 255) *rowptr_last = ts[255];
}

__global__ void scan3(int* __restrict__ rowptr, const int* __restrict__ blockoff, int N) {
    int i = blockIdx.x * blockDim.x + threadIdx.x;
    if (i < N) rowptr[i] += blockoff[i >> 10];
}

// csr_fill precomputes per-edge weight dinv[src]*dinv[dst]; stores {src, w}.
__global__ void csr_fill(const int* __restrict__ src, const int* __restrict__ dst,
                         const int* __restrict__ rowptr, int* __restrict__ fill,
                         int2* __restrict__ csr_iw, const float* __restrict__ dinv,
                         int E) {
    int e = blockIdx.x * blockDim.x + threadIdx.x;
    if (e >= E) return;
    int d = dst[e];
    int s = src[e];
    int pos = rowptr[d] + atomicAdd(&fill[d], 1);
    float w = dinv[d] * dinv[s];
    csr_iw[pos] = make_int2(s, __float_as_int(w));
}

// ---------------------------------------------------------------------------
// casts
// ---------------------------------------------------------------------------
__global__ void cast_bf16(const float* __restrict__ x, short* __restrict__ y, int n4) {
    int i = blockIdx.x * blockDim.x + threadIdx.x;
    if (i >= n4) return;
    float4 v = ((const float4*)x)[i];
    short4 o;
    o.x = f2bf(v.x); o.y = f2bf(v.y); o.z = f2bf(v.z); o.w = f2bf(v.w);
    ((short4*)y)[i] = o;
}

__global__ void wt_cast(const float* __restrict__ W, short* __restrict__ Wt, int K, int NC) {
    int idx = blockIdx.x * blockDim.x + threadIdx.x;
    if (idx >= K * NC) return;
    int n = idx / K, k = idx % K;
    Wt[idx] = f2bf(W[k * NC + n]);
}

// ---------------------------------------------------------------------------
// bf16 MFMA GEMM (plain A): C[M,NC](bf16) = A[M,K] @ Wt[NC,K]^T, double-buffered
// ---------------------------------------------------------------------------
__global__ __launch_bounds__(256)
void gemm_mfma(const short* __restrict__ A, const short* __restrict__ Bt,
               short* __restrict__ C, int M, int K, int NC) {
    __shared__ short As[2][128 * 32];
    __shared__ short Bs[2][128 * 32];
    const int tid  = threadIdx.x;
    const int lane = tid & 63;
    const int w    = tid >> 6;
    const int wm   = w & 1, wn = w >> 1;
    const int bm   = blockIdx.x * 128;
    const int bn   = blockIdx.y * 128;

    const int srow = w * 16 + (lane >> 2);
    const int scol = (lane & 3) * 8;

    const int ga_r0 = (bm + srow      < M) ? bm + srow      : M - 1;
    const int ga_r1 = (bm + srow + 64 < M) ? bm + srow + 64 : M - 1;
    const size_t arow0 = (size_t)ga_r0 * K;
    const size_t arow1 = (size_t)ga_r1 * K;
    const size_t brow0 = (size_t)(bn + srow) * K;
    const size_t brow1 = (size_t)(bn + srow + 64) * K;

    auto stage = [&](int buf, int k0) {
        __builtin_amdgcn_global_load_lds(
            (const __attribute__((address_space(1))) void*)(A + arow0 + k0 + scol),
            (__attribute__((address_space(3))) void*)&As[buf][srow * 32 + scol], 16, 0, 0);
        __builtin_amdgcn_global_load_lds(
            (const __attribute__((address_space(1))) void*)(A + arow1 + k0 + scol),
            (__attribute__((address_space(3))) void*)&As[buf][(srow + 64) * 32 + scol], 16, 0, 0);
        __builtin_amdgcn_global_load_lds(
            (const __attribute__((address_space(1))) void*)(Bt + brow0 + k0 + scol),
            (__attribute__((address_space(3))) void*)&Bs[buf][srow * 32 + scol], 16, 0, 0);
        __builtin_amdgcn_global_load_lds(
            (const __attribute__((address_space(1))) void*)(Bt + brow1 + k0 + scol),
            (__attribute__((address_space(3))) void*)&Bs[buf][(srow + 64) * 32 + scol], 16, 0, 0);
    };

    f32x4 acc[4][4];
#pragma unroll
    for (int i = 0; i < 4; ++i)
#pragma unroll
        for (int j = 0; j < 4; ++j) acc[i][j] = (f32x4){0.f, 0.f, 0.f, 0.f};

    const int frow = lane & 15;
    const int kg   = (lane >> 4) * 8;
    const int nk   = K >> 5;

    stage(0, 0);
    __syncthreads();

    for (int kk = 0; kk < nk; ++kk) {
        const int cur = kk & 1;
        if (kk + 1 < nk) stage(cur ^ 1, (kk + 1) << 5);

        bf16x8 af[4], bfr[4];
#pragma unroll
        for (int i = 0; i < 4; ++i)
            af[i] = *(const bf16x8*)&As[cur][(wm * 64 + i * 16 + frow) * 32 + kg];
#pragma unroll
        for (int j = 0; j < 4; ++j)
            bfr[j] = *(const bf16x8*)&Bs[cur][(wn * 64 + j * 16 + frow) * 32 + kg];
#pragma unroll
        for (int i = 0; i < 4; ++i)
#pragma unroll
            for (int j = 0; j < 4; ++j)
                acc[i][j] = __builtin_amdgcn_mfma_f32_16x16x32_bf16(
                    af[i], bfr[j], acc[i][j], 0, 0, 0);

        __syncthreads();
    }

    const int row_base = bm + wm * 64 + (lane >> 4) * 4;
    const int col_base = bn + wn * 64 + (lane & 15);
#pragma unroll
    for (int i = 0; i < 4; ++i) {
#pragma unroll
        for (int r = 0; r < 4; ++r) {
            int row = row_base + i * 16 + r;
            if (row < M) {
                short* cp = C + (size_t)row * NC + col_base;
#pragma unroll
                for (int j = 0; j < 4; ++j) cp[j * 16] = f2bf(acc[i][j][r]);
            }
        }
    }
}

// ---------------------------------------------------------------------------
// GEMM with fused LN+leakyReLU on A: A' = leaky(A*s[c] + t[c]), st = {s[256],t[256]}.
// A staged via registers (load bf16x8 -> fma -> max -> cvt_pk -> ds_write_b128);
// B stays on global_load_lds. Deletes the standalone ln_apply pass.
// ---------------------------------------------------------------------------
__global__ __launch_bounds__(256)
void gemm_mfma_ln(const short* __restrict__ A, const short* __restrict__ Bt,
                  short* __restrict__ C, const float* __restrict__ st,
                  int M, int K, int NC) {
    __shared__ short As[2][128 * 32];
    __shared__ short Bs[2][128 * 32];
    const int tid  = threadIdx.x;
    const int lane = tid & 63;
    const int w    = tid >> 6;
    const int wm   = w & 1, wn = w >> 1;
    const int bm   = blockIdx.x * 128;
    const int bn   = blockIdx.y * 128;

    const int srow = w * 16 + (lane >> 2);
    const int scol = (lane & 3) * 8;

    const int ga_r0 = (bm + srow      < M) ? bm + srow      : M - 1;
    const int ga_r1 = (bm + srow + 64 < M) ? bm + srow + 64 : M - 1;
    const size_t arow0 = (size_t)ga_r0 * K;
    const size_t arow1 = (size_t)ga_r1 * K;
    const size_t brow0 = (size_t)(bn + srow) * K;
    const size_t brow1 = (size_t)(bn + srow + 64) * K;

    auto stageB = [&](int buf, int k0) {
        __builtin_amdgcn_global_load_lds(
            (const __attribute__((address_space(1))) void*)(Bt + brow0 + k0 + scol),
            (__attribute__((address_space(3))) void*)&Bs[buf][srow * 32 + scol], 16, 0, 0);
        __builtin_amdgcn_global_load_lds(
            (const __attribute__((address_space(1))) void*)(Bt + brow1 + k0 + scol),
            (__attribute__((address_space(3))) void*)&Bs[buf][(srow + 64) * 32 + scol], 16, 0, 0);
    };

    auto stA = [&](int buf, int k0, bf16x8 a0, bf16x8 a1) {
        const float* sp = st + k0 + scol;
        const float* tp = st + 256 + k0 + scol;
        float4 s0 = *(const float4*)sp,       s1 = *(const float4*)(sp + 4);
        float4 t0 = *(const float4*)tp,       t1 = *(const float4*)(tp + 4);
        float sv[8] = {s0.x, s0.y, s0.z, s0.w, s1.x, s1.y, s1.z, s1.w};
        float tv[8] = {t0.x, t0.y, t0.z, t0.w, t1.x, t1.y, t1.z, t1.w};
        unsigned p0[4], p1[4];
#pragma unroll
        for (int q = 0; q < 4; ++q) {
            float x0 = fmaf(bf2f(a0[2*q]),     sv[2*q],     tv[2*q]);
            float x1 = fmaf(bf2f(a0[2*q + 1]), sv[2*q + 1], tv[2*q + 1]);
            x0 = fmaxf(x0, x0 * SLOPE);
            x1 = fmaxf(x1, x1 * SLOPE);
            p0[q] = cvt_pk_bf16(x0, x1);
            float y0 = fmaf(bf2f(a1[2*q]),     sv[2*q],     tv[2*q]);
            float y1 = fmaf(bf2f(a1[2*q + 1]), sv[2*q + 1], tv[2*q + 1]);
            y0 = fmaxf(y0, y0 * SLOPE);
            y1 = fmaxf(y1, y1 * SLOPE);
            p1[q] = cvt_pk_bf16(y0, y1);
        }
        *(int4*)&As[buf][srow * 32 + scol]        = make_int4(p0[0], p0[1], p0[2], p0[3]);
        *(int4*)&As[buf][(srow + 64) * 32 + scol] = make_int4(p1[0], p1[1], p1[2], p1[3]);
    };

    f32x4 acc[4][4];
#pragma unroll
    for (int i = 0; i < 4; ++i)
#pragma unroll
        for (int j = 0; j < 4; ++j) acc[i][j] = (f32x4){0.f, 0.f, 0.f, 0.f};

    const int frow = lane & 15;
    const int kg   = (lane >> 4) * 8;
    const int nk   = K >> 5;

    {
        bf16x8 a0 = *(const bf16x8*)(A + arow0 + scol);
        bf16x8 a1 = *(const bf16x8*)(A + arow1 + scol);
        stageB(0, 0);
        stA(0, 0, a0, a1);
    }
    __syncthreads();

    for (int kk = 0; kk < nk; ++kk) {
        const int cur = kk & 1;
        const bool pre = (kk + 1 < nk);
        bf16x8 a0, a1;
        if (pre) {
            const int k1 = (kk + 1) << 5;
            a0 = *(const bf16x8*)(A + arow0 + k1 + scol);   // issued early
            a1 = *(const bf16x8*)(A + arow1 + k1 + scol);
            stageB(cur ^ 1, k1);
        }

        bf16x8 af[4], bfr[4];
#pragma unroll
        for (int i = 0; i < 4; ++i)
            af[i] = *(const bf16x8*)&As[cur][(wm * 64 + i * 16 + frow) * 32 + kg];
#pragma unroll
        for (int j = 0; j < 4; ++j)
            bfr[j] = *(const bf16x8*)&Bs[cur][(wn * 64 + j * 16 + frow) * 32 + kg];
#pragma unroll
        for (int i = 0; i < 4; ++i)
#pragma unroll
            for (int j = 0; j < 4; ++j)
                acc[i][j] = __builtin_amdgcn_mfma_f32_16x16x32_bf16(
                    af[i], bfr[j], acc[i][j], 0, 0, 0);

        if (pre) stA(cur ^ 1, (kk + 1) << 5, a0, a1);   // write-late
        __syncthreads();
    }

    const int row_base = bm + wm * 64 + (lane >> 4) * 4;
    const int col_base = bn + wn * 64 + (lane & 15);
#pragma unroll
    for (int i = 0; i < 4; ++i) {
#pragma unroll
        for (int r = 0; r < 4; ++r) {
            int row = row_base + i * 16 + r;
            if (row < M) {
                short* cp = C + (size_t)row * NC + col_base;
#pragma unroll
                for (int j = 0; j < 4; ++j) cp[j * 16] = f2bf(acc[i][j][r]);
            }
        }
    }
}

// ---------------------------------------------------------------------------
// CSR aggregation (bf16 gather, fp32 acc) + per-block LN partial stats.
// R1-proven: 4-deep unroll, contention-free psum/psumsq writes, NO fences,
// NO device-scope atomics (R4's per-block __threadfence invalidated per-XCD
// L2 12500x per dispatch -> 7x regression).
// ---------------------------------------------------------------------------
__global__ __launch_bounds__(256)
void agg_ln_csr(const short* __restrict__ h, const int* __restrict__ rowptr,
                const int2* __restrict__ csr_iw, const float* __restrict__ dinv,
                const float* __restrict__ bias, short* __restrict__ agg,
                float* __restrict__ psum, float* __restrict__ psumsq, int N) {
    constexpr int TPN = 32;                 // D=256 bf16 -> 32 x 16B
    int t = blockIdx.x * 256 + threadIdx.x;
    int n = t / TPN, l = t % TPN;
    float acc[8] = {0.f, 0.f, 0.f, 0.f, 0.f, 0.f, 0.f, 0.f};
    if (n < N) {
        const bf16x8* h8 = (const bf16x8*)h;   // row = 32 vectors
        float di = dinv[n];
        float sl2 = di * di;
        bf16x8 sv = h8[(size_t)n * TPN + l];
        const float* bp = bias + l * 8;
#pragma unroll
        for (int c = 0; c < 8; ++c) acc[c] = bf2f(sv[c]) * sl2 + bp[c];
        int j = rowptr[n], j1 = rowptr[n + 1];
        for (; j + 3 < j1; j += 4) {
            int2 e0 = csr_iw[j],     e1 = csr_iw[j + 1];
            int2 e2 = csr_iw[j + 2], e3 = csr_iw[j + 3];
            float w0 = __int_as_float(e0.y), w1 = __int_as_float(e1.y);
            float w2 = __int_as_float(e2.y), w3 = __int_as_float(e3.y);
            bf16x8 v0 = h8[(size_t)e0.x * TPN + l];
            bf16x8 v1 = h8[(size_t)e1.x * TPN + l];
            bf16x8 v2 = h8[(size_t)e2.x * TPN + l];
            bf16x8 v3 = h8[(size_t)e3.x * TPN + l];
#pragma unroll
            for (int c = 0; c < 8; ++c)
                acc[c] += bf2f(v0[c]) * w0 + bf2f(v1[c]) * w1 +
                          bf2f(v2[c]) * w2 + bf2f(v3[c]) * w3;
        }
        if (j + 1 < j1) {
            int2 e0 = csr_iw[j], e1 = csr_iw[j + 1];
            float w0 = __int_as_float(e0.y), w1 = __int_as_float(e1.y);
            bf16x8 v0 = h8[(size_t)e0.x * TPN + l];
            bf16x8 v1 = h8[(size_t)e1.x * TPN + l];
#pragma unroll
            for (int c = 0; c < 8; ++c)
                acc[c] += bf2f(v0[c]) * w0 + bf2f(v1[c]) * w1;
            j += 2;
        }
        if (j < j1) {
            int2 e0 = csr_iw[j];
            float w0 = __int_as_float(e0.y);
            bf16x8 v0 = h8[(size_t)e0.x * TPN + l];
#pragma unroll
            for (int c = 0; c < 8; ++c) acc[c] += bf2f(v0[c]) * w0;
        }
        bf16x8 o;
#pragma unroll
        for (int c = 0; c < 8; ++c) o[c] = f2bf(acc[c]);
        ((bf16x8*)agg)[(size_t)n * TPN + l] = o;
    }
    // LN partial stats -> per-block array (contention-free)
    float s = 0.f, q = 0.f;
#pragma unroll
    for (int c = 0; c < 8; ++c) { s += acc[c]; q += acc[c] * acc[c]; }
#pragma unroll
    for (int off = 32; off; off >>= 1) {
        s += __shfl_down(s, off);
        q += __shfl_down(q, off);
    }
    __shared__ float ss[4], qq[4];
    int wid = threadIdx.x >> 6, lane = threadIdx.x & 63;
    if (lane == 0) { ss[wid] = s; qq[wid] = q; }
    __syncthreads();
    if (threadIdx.x == 0) {
        psum[blockIdx.x]   = ss[0] + ss[1] + ss[2] + ss[3];
        psumsq[blockIdx.x] = qq[0] + qq[1] + qq[2] + qq[3];
    }
}

// ---------------------------------------------------------------------------
// LN finalize: reduce per-block partials -> per-channel LN coefficients
// s[c]=inv*gamma[c], t[c]=beta[c]-mu*inv*gamma[c]  (consumed by gemm_mfma_ln)
// ---------------------------------------------------------------------------
__global__ __launch_bounds__(1024)
void ln_finalize_st(const float* __restrict__ psum, const float* __restrict__ psumsq,
                    int nb, const float* __restrict__ gamma,
                    const float* __restrict__ beta, float* __restrict__ st, double M) {
    double s = 0.0, q = 0.0;
    for (int i = threadIdx.x; i < nb; i += 1024) {
        s += (double)psum[i];
        q += (double)psumsq[i];
    }
#pragma unroll
    for (int off = 32; off; off >>= 1) {
        s += __shfl_down(s, off);
        q += __shfl_down(q, off);
    }
    __shared__ double ss[16], qq[16];
    __shared__ float mi[2];
    int wid = threadIdx.x >> 6, lane = threadIdx.x & 63;
    if (lane == 0) { ss[wid] = s; qq[wid] = q; }
    __syncthreads();
    if (threadIdx.x == 0) {
        double S = 0.0, Q = 0.0;
        for (int i = 0; i < 16; ++i) { S += ss[i]; Q += qq[i]; }
        double mu  = S / M;
        double var = Q / M - mu * mu;
        if (var < 0.0) var = 0.0;
        mi[0] = (float)mu;
        mi[1] = 1.0f / ((float)sqrt(var) + EPS);
    }
    __syncthreads();
    if (threadIdx.x < 256) {
        int c = threadIdx.x;
        float mu = mi[0], inv = mi[1];
        float gv = gamma[c], bv = beta[c];
        st[c]       = inv * gv;
        st[256 + c] = bv - mu * inv * gv;
    }
}

// final layer: D=128, 16 lanes/node (16B), 4 nodes/wave, fp32 out, no stats
__global__ __launch_bounds__(256)
void agg_out_csr(const short* __restrict__ h, const int* __restrict__ rowptr,
                 const int2* __restrict__ csr_iw, const float* __restrict__ dinv,
                 const float* __restrict__ bias, float* __restrict__ out, int N) {
    constexpr int TPN = 16;                 // D=128 bf16 -> 16 x 16B
    int t = blockIdx.x * 256 + threadIdx.x;
    int n = t / TPN, l = t % TPN;
    if (n >= N) return;
    const bf16x8* h8 = (const bf16x8*)h;
    float di = dinv[n];
    float sl2 = di * di;
    bf16x8 sv = h8[(size_t)n * TPN + l];
    const float* bp = bias + l * 8;
    float acc[8];
#pragma unroll
    for (int c = 0; c < 8; ++c) acc[c] = bf2f(sv[c]) * sl2 + bp[c];
    int j = rowptr[n], j1 = rowptr[n + 1];
    for (; j + 3 < j1; j += 4) {
        int2 e0 = csr_iw[j],     e1 = csr_iw[j + 1];
        int2 e2 = csr_iw[j + 2], e3 = csr_iw[j + 3];
        float w0 = __int_as_float(e0.y), w1 = __int_as_float(e1.y);
        float w2 = __int_as_float(e2.y), w3 = __int_as_float(e3.y);
        bf16x8 v0 = h8[(size_t)e0.x * TPN + l];
        bf16x8 v1 = h8[(size_t)e1.x * TPN + l];
        bf16x8 v2 = h8[(size_t)e2.x * TPN + l];
        bf16x8 v3 = h8[(size_t)e3.x * TPN + l];
#pragma unroll
        for (int c = 0; c < 8; ++c)
            acc[c] += bf2f(v0[c]) * w0 + bf2f(v1[c]) * w1 +
                      bf2f(v2[c]) * w2 + bf2f(v3[c]) * w3;
    }
    if (j + 1 < j1) {
        int2 e0 = csr_iw[j], e1 = csr_iw[j + 1];
        float w0 = __int_as_float(e0.y), w1 = __int_as_float(e1.y);
        bf16x8 v0 = h8[(size_t)e0.x * TPN + l];
        bf16x8 v1 = h8[(size_t)e1.x * TPN + l];
#pragma unroll
        for (int c = 0; c < 8; ++c)
            acc[c] += bf2f(v0[c]) * w0 + bf2f(v1[c]) * w1;
        j += 2;
    }
    if (j < j1) {
        int2 e0 = csr_iw[j];
        float w0 = __int_as_float(e0.y);
        bf16x8 v0 = h8[(size_t)e0.x * TPN + l];
#pragma unroll
        for (int c = 0; c < 8; ++c) acc[c] += bf2f(v0[c]) * w0;
    }
    float4* op = (float4*)(out + (size_t)n * 128 + l * 8);
    op[0] = make_float4(acc[0], acc[1], acc[2], acc[3]);
    op[1] = make_float4(acc[4], acc[5], acc[6], acc[7]);
}

// ---------------------------------------------------------------------------
// launcher
// ---------------------------------------------------------------------------
extern "C" void kernel_launch(void* const* d_in, const int* in_sizes, int n_in,
                              void* d_out, int out_size, void* d_ws, size_t ws_size,
                              hipStream_t stream) {
    const float* x   = (const float*)d_in[0];
    const int*   ei  = (const int*)d_in[1];
    const float* W1  = (const float*)d_in[2];
    const float* b1  = (const float*)d_in[3];
    const float* g1  = (const float*)d_in[4];
    const float* be1 = (const float*)d_in[5];
    const float* W2  = (const float*)d_in[6];
    const float* b2  = (const float*)d_in[7];
    const float* g2  = (const float*)d_in[8];
    const float* be2 = (const float*)d_in[9];
    const float* W3  = (const float*)d_in[10];
    const float* b3  = (const float*)d_in[11];
    const float* g3  = (const float*)d_in[12];
    const float* be3 = (const float*)d_in[13];
    const float* W4  = (const float*)d_in[14];
    const float* b4  = (const float*)d_in[15];

    const int N = in_sizes[0] / DH;   // 100000
    const int E = in_sizes[1] / 2;    // 800000
    const int* src = ei;
    const int* dst = ei + E;
    const int nb = (N + 1023) / 1024;
    const int nagg = (N * 32 + 255) / 256;   // agg_ln_csr blocks (12500)

    char* w = (char*)d_ws;
    size_t off = 0;
    auto alloc = [&](size_t bytes) { char* p = w + off; off = (off + bytes + 255) & ~(size_t)255; return p; };
    int*    deg      = (int*)alloc((size_t)N * 4);
    int*    fill     = (int*)alloc((size_t)N * 4);
    int*    rowptr   = (int*)alloc((size_t)(N + 1) * 4);
    int*    blocksum = (int*)alloc(256 * 4);
    int*    blockoff = (int*)alloc(256 * 4);
    float*  dinv     = (float*)alloc((size_t)N * 4);
    float*  psum     = (float*)alloc((size_t)nagg * 4);
    float*  psumsq   = (float*)alloc((size_t)nagg * 4);
    float*  st1      = (float*)alloc(512 * 4);
    float*  st2      = (float*)alloc(512 * 4);
    float*  st3      = (float*)alloc(512 * 4);
    int2*   csr_iw   = (int2*)alloc((size_t)E * 8);
    short*  Wt1      = (short*)alloc((size_t)DH * DH * 2);
    short*  Wt2      = (short*)alloc((size_t)DH * DH * 2);
    short*  Wt3      = (short*)alloc((size_t)DH * DH * 2);
    short*  Wt4      = (short*)alloc((size_t)DZ * DH * 2);
    short*  actbf    = (short*)alloc((size_t)N * DH * 2);
    short*  hbf      = (short*)alloc((size_t)N * DH * 2);
    short*  aggb     = (short*)alloc((size_t)N * DH * 2);

    // ---- one memset for deg + fill (contiguous) ----
    hipMemsetAsync(deg, 0, (size_t)((char*)rowptr - (char*)deg), stream);

    // ---- degree, dinv, CSR build ----
    deg_count_i<<<(E + 255) / 256, 256, 0, stream>>>(dst, deg, E);
    make_dinv<<<(N + 255) / 256, 256, 0, stream>>>(deg, dinv, N);
    scan1<<<nb, 256, 0, stream>>>(deg, rowptr, blocksum, N);
    scan2<<<1, 256, 0, stream>>>(blocksum, blockoff, nb, rowptr + N);
    scan3<<<(N + 255) / 256, 256, 0, stream>>>(rowptr, blockoff, N);
    csr_fill<<<(E + 255) / 256, 256, 0, stream>>>(src, dst, rowptr, fill, csr_iw, dinv, E);

    // ---- weight transpose+cast, input cast ----
    wt_cast<<<(DH * DH + 255) / 256, 256, 0, stream>>>(W1, Wt1, DH, DH);
    wt_cast<<<(DH * DH + 255) / 256, 256, 0, stream>>>(W2, Wt2, DH, DH);
    wt_cast<<<(DH * DH + 255) / 256, 256, 0, stream>>>(W3, Wt3, DH, DH);
    wt_cast<<<(DH * DZ + 255) / 256, 256, 0, stream>>>(W4, Wt4, DH, DZ);
    cast_bf16<<<(N * DH / 4 + 255) / 256, 256, 0, stream>>>(x, actbf, N * DH / 4);

    const int gmM = (N + 127) / 128;
    const double M = (double)N * (double)DH;

    // layer 1: plain gemm on cast(x)
    gemm_mfma<<<dim3(gmM, DH / 128), 256, 0, stream>>>(actbf, Wt1, hbf, N, DH, DH);
    agg_ln_csr<<<nagg, 256, 0, stream>>>(hbf, rowptr, csr_iw, dinv, b1, aggb,
                                         psum, psumsq, N);
    ln_finalize_st<<<1, 1024, 0, stream>>>(psum, psumsq, nagg, g1, be1, st1, M);
    // layer 2: LN1+leaky fused into gemm A-staging
    gemm_mfma_ln<<<dim3(gmM, DH / 128), 256, 0, stream>>>(aggb, Wt2, hbf, st1, N, DH, DH);
    agg_ln_csr<<<nagg, 256, 0, stream>>>(hbf, rowptr, csr_iw, dinv, b2, aggb,
                                         psum, psumsq, N);
    ln_finalize_st<<<1, 1024, 0, stream>>>(psum, psumsq, nagg, g2, be2, st2, M);
    // layer 3
    gemm_mfma_ln<<<dim3(gmM, DH / 128), 256, 0, stream>>>(aggb, Wt3, hbf, st2, N, DH, DH);
    agg_ln_csr<<<nagg, 256, 0, stream>>>(hbf, rowptr, csr_iw, dinv, b3, aggb,
                                         psum, psumsq, N);
    ln_finalize_st<<<1, 1024, 0, stream>>>(psum, psumsq, nagg, g3, be3, st3, M);
    // final conv: LN3+leaky fused, DH -> DZ
    gemm_mfma_ln<<<dim3(gmM, DZ / 128), 256, 0, stream>>>(aggb, Wt4, hbf, st3, N, DH, DZ);
    float* out = (float*)d_out;
    int naggz = (N * 16 + 255) / 256;
    agg_out_csr<<<naggz, 256, 0, stream>>>(hbf, rowptr, csr_iw, dinv, b4, out, N);
}

// Round 6
// 650.108 us; speedup vs baseline: 3.0293x; 1.0513x over previous
//
#include <hip/hip_runtime.h>
#include <math.h>

constexpr int DH  = 256;
constexpr int DZ  = 128;
constexpr float EPS   = 1e-5f;
constexpr float SLOPE = 0.01f;

typedef __attribute__((ext_vector_type(8))) short bf16x8;
typedef __attribute__((ext_vector_type(4))) float f32x4;

__device__ __forceinline__ short f2bf(float f) {
    union { float f; unsigned u; } v; v.f = f;
    unsigned r = v.u + 0x7fffu + ((v.u >> 16) & 1u);   // RNE
    return (short)(r >> 16);
}
__device__ __forceinline__ float bf2f(short s) {
    union { unsigned u; float f; } v;
    v.u = ((unsigned)(unsigned short)s) << 16;
    return v.f;
}
__device__ __forceinline__ unsigned cvt_pk_bf16(float lo, float hi) {
    unsigned r;
    asm volatile("v_cvt_pk_bf16_f32 %0, %1, %2" : "=v"(r) : "v"(lo), "v"(hi));
    return r;
}

// ---------------------------------------------------------------------------
// degree (int) / dinv
// ---------------------------------------------------------------------------
__global__ void deg_count_i(const int* __restrict__ dst, int* __restrict__ deg, int E) {
    int e = blockIdx.x * blockDim.x + threadIdx.x;
    if (e < E) atomicAdd(&deg[dst[e]], 1);
}

__global__ void make_dinv(const int* __restrict__ deg, float* __restrict__ dinv, int N) {
    int i = blockIdx.x * blockDim.x + threadIdx.x;
    if (i < N) dinv[i] = rsqrtf((float)deg[i] + 1.0f);
}

// ---------------------------------------------------------------------------
// exclusive scan of deg[N] -> rowptr
// ---------------------------------------------------------------------------
__global__ __launch_bounds__(256)
void scan1(const int* __restrict__ deg, int* __restrict__ rowptr,
           int* __restrict__ blocksum, int N) {
    __shared__ int ts[256];
    int base = blockIdx.x * 1024 + threadIdx.x * 4;
    int v[4], s = 0;
#pragma unroll
    for (int i = 0; i < 4; ++i) {
        v[i] = (base + i < N) ? deg[base + i] : 0;
        s += v[i];
    }
    ts[threadIdx.x] = s;
    __syncthreads();
    for (int off = 1; off < 256; off <<= 1) {
        int t = 0;
        if ((int)threadIdx.x >= off) t = ts[threadIdx.x - off];
        __syncthreads();
        if ((int)threadIdx.x >= off) ts[threadIdx.x] += t;
        __syncthreads();
    }
    int run = ts[threadIdx.x] - s;
#pragma unroll
    for (int i = 0; i < 4; ++i) {
        if (base + i < N) rowptr[base + i] = run;
        run += v[i];
    }
    if (threadIdx.x == 255) blocksum[blockIdx.x] = ts[255];
}

__global__ __launch_bounds__(256)
void scan2(const int* __restrict__ blocksum, int* __restrict__ blockoff,
           int nb, int* __restrict__ rowptr_last) {
    __shared__ int ts[256];
    int v = ((int)threadIdx.x < nb) ? blocksum[threadIdx.x] : 0;
    ts[threadIdx.x] = v;
    __syncthreads();
    for (int off = 1; off < 256; off <<= 1) {
        int t = 0;
        if ((int)threadIdx.x >= off) t = ts[threadIdx.x - off];
        __syncthreads();
        if ((int)threadIdx.x >= off) ts[threadIdx.x] += t;
        __syncthreads();
    }
    blockoff[threadIdx.x] = ts[threadIdx.x] - v;
    if (threadIdx.x == 255) *rowptr_last = ts[255];
}

__global__ void scan3(int* __restrict__ rowptr, const int* __restrict__ blockoff, int N) {
    int i = blockIdx.x * blockDim.x + threadIdx.x;
    if (i < N) rowptr[i] += blockoff[i >> 10];
}

// csr_fill precomputes per-edge weight dinv[src]*dinv[dst]; stores {src, w}.
__global__ void csr_fill(const int* __restrict__ src, const int* __restrict__ dst,
                         const int* __restrict__ rowptr, int* __restrict__ fill,
                         int2* __restrict__ csr_iw, const float* __restrict__ dinv,
                         int E) {
    int e = blockIdx.x * blockDim.x + threadIdx.x;
    if (e >= E) return;
    int d = dst[e];
    int s = src[e];
    int pos = rowptr[d] + atomicAdd(&fill[d], 1);
    float w = dinv[d] * dinv[s];
    csr_iw[pos] = make_int2(s, __float_as_int(w));
}

__global__ void wt_cast(const float* __restrict__ W, short* __restrict__ Wt, int K, int NC) {
    int idx = blockIdx.x * blockDim.x + threadIdx.x;
    if (idx >= K * NC) return;
    int n = idx / K, k = idx % K;
    Wt[idx] = f2bf(W[k * NC + n]);
}

// ---------------------------------------------------------------------------
// WIDE GEMM, layer 1: C[M,256](bf16) = cast(Xf32[M,256]) @ Wt[256,256]^T.
// 128x256 block, 512 threads (8 waves, 2x4). A reg-staged (f32->bf16 fused,
// deletes the standalone cast pass); B via global_load_lds. grid.y == 1 so
// each A panel is read exactly once.
// ---------------------------------------------------------------------------
__global__ __launch_bounds__(512)
void gemm_cast_w(const float* __restrict__ A, const short* __restrict__ Bt,
                 short* __restrict__ C, int M) {
    constexpr int K = 256;
    constexpr int NC = 256;
    __shared__ short As[2][128 * 32];
    __shared__ short Bs[2][256 * 32];
    const int tid  = threadIdx.x;
    const int lane = tid & 63;
    const int w    = tid >> 6;           // 0..7
    const int wm   = w & 1, wn = w >> 1; // 2 x 4
    const int bm   = blockIdx.x * 128;

    const int srow = tid >> 2;           // 0..127
    const int scol = (tid & 3) * 8;      // 0,8,16,24

    const int ga_r = (bm + srow < M) ? bm + srow : M - 1;
    const size_t arow  = (size_t)ga_r * K;
    const size_t brow0 = (size_t)srow * K;
    const size_t brow1 = (size_t)(srow + 128) * K;

    auto stageB = [&](int buf, int k0) {
        __builtin_amdgcn_global_load_lds(
            (const __attribute__((address_space(1))) void*)(Bt + brow0 + k0 + scol),
            (__attribute__((address_space(3))) void*)&Bs[buf][srow * 32 + scol], 16, 0, 0);
        __builtin_amdgcn_global_load_lds(
            (const __attribute__((address_space(1))) void*)(Bt + brow1 + k0 + scol),
            (__attribute__((address_space(3))) void*)&Bs[buf][(srow + 128) * 32 + scol], 16, 0, 0);
    };
    auto stA = [&](int buf, float4 f0, float4 f1) {
        unsigned p0 = cvt_pk_bf16(f0.x, f0.y);
        unsigned p1 = cvt_pk_bf16(f0.z, f0.w);
        unsigned p2 = cvt_pk_bf16(f1.x, f1.y);
        unsigned p3 = cvt_pk_bf16(f1.z, f1.w);
        *(int4*)&As[buf][srow * 32 + scol] = make_int4(p0, p1, p2, p3);
    };

    f32x4 acc[4][4];
#pragma unroll
    for (int i = 0; i < 4; ++i)
#pragma unroll
        for (int j = 0; j < 4; ++j) acc[i][j] = (f32x4){0.f, 0.f, 0.f, 0.f};

    const int frow = lane & 15;
    const int kg   = (lane >> 4) * 8;
    constexpr int nk = K / 32;

    {
        float4 f0 = *(const float4*)(A + arow + scol);
        float4 f1 = *(const float4*)(A + arow + scol + 4);
        stageB(0, 0);
        stA(0, f0, f1);
    }
    __syncthreads();

    for (int kk = 0; kk < nk; ++kk) {
        const int cur = kk & 1;
        const bool pre = (kk + 1 < nk);
        float4 f0, f1;
        if (pre) {
            const int k1 = (kk + 1) << 5;
            f0 = *(const float4*)(A + arow + k1 + scol);
            f1 = *(const float4*)(A + arow + k1 + scol + 4);
            stageB(cur ^ 1, k1);
        }

        bf16x8 af[4], bfr[4];
#pragma unroll
        for (int i = 0; i < 4; ++i)
            af[i] = *(const bf16x8*)&As[cur][(wm * 64 + i * 16 + frow) * 32 + kg];
#pragma unroll
        for (int j = 0; j < 4; ++j)
            bfr[j] = *(const bf16x8*)&Bs[cur][(wn * 64 + j * 16 + frow) * 32 + kg];
#pragma unroll
        for (int i = 0; i < 4; ++i)
#pragma unroll
            for (int j = 0; j < 4; ++j)
                acc[i][j] = __builtin_amdgcn_mfma_f32_16x16x32_bf16(
                    af[i], bfr[j], acc[i][j], 0, 0, 0);

        if (pre) stA(cur ^ 1, f0, f1);
        __syncthreads();
    }

    const int row_base = bm + wm * 64 + (lane >> 4) * 4;
    const int col_base = wn * 64 + (lane & 15);
#pragma unroll
    for (int i = 0; i < 4; ++i) {
#pragma unroll
        for (int r = 0; r < 4; ++r) {
            int row = row_base + i * 16 + r;
            if (row < M) {
                short* cp = C + (size_t)row * NC + col_base;
#pragma unroll
                for (int j = 0; j < 4; ++j) cp[j * 16] = f2bf(acc[i][j][r]);
            }
        }
    }
}

// ---------------------------------------------------------------------------
// WIDE GEMM with fused LN+leakyReLU on A (layers 2,3): 128x256 block,
// 512 threads, A read once. A' = leaky(A*s[c] + t[c]).
// ---------------------------------------------------------------------------
__global__ __launch_bounds__(512)
void gemm_ln_w(const short* __restrict__ A, const short* __restrict__ Bt,
               short* __restrict__ C, const float* __restrict__ st, int M) {
    constexpr int K = 256;
    constexpr int NC = 256;
    __shared__ short As[2][128 * 32];
    __shared__ short Bs[2][256 * 32];
    const int tid  = threadIdx.x;
    const int lane = tid & 63;
    const int w    = tid >> 6;
    const int wm   = w & 1, wn = w >> 1;
    const int bm   = blockIdx.x * 128;

    const int srow = tid >> 2;
    const int scol = (tid & 3) * 8;

    const int ga_r = (bm + srow < M) ? bm + srow : M - 1;
    const size_t arow  = (size_t)ga_r * K;
    const size_t brow0 = (size_t)srow * K;
    const size_t brow1 = (size_t)(srow + 128) * K;

    auto stageB = [&](int buf, int k0) {
        __builtin_amdgcn_global_load_lds(
            (const __attribute__((address_space(1))) void*)(Bt + brow0 + k0 + scol),
            (__attribute__((address_space(3))) void*)&Bs[buf][srow * 32 + scol], 16, 0, 0);
        __builtin_amdgcn_global_load_lds(
            (const __attribute__((address_space(1))) void*)(Bt + brow1 + k0 + scol),
            (__attribute__((address_space(3))) void*)&Bs[buf][(srow + 128) * 32 + scol], 16, 0, 0);
    };
    auto stA = [&](int buf, int k0, bf16x8 a0) {
        const float* sp = st + k0 + scol;
        const float* tp = st + 256 + k0 + scol;
        float4 s0 = *(const float4*)sp, s1 = *(const float4*)(sp + 4);
        float4 t0 = *(const float4*)tp, t1 = *(const float4*)(tp + 4);
        float sv[8] = {s0.x, s0.y, s0.z, s0.w, s1.x, s1.y, s1.z, s1.w};
        float tv[8] = {t0.x, t0.y, t0.z, t0.w, t1.x, t1.y, t1.z, t1.w};
        unsigned p[4];
#pragma unroll
        for (int q = 0; q < 4; ++q) {
            float x0 = fmaf(bf2f(a0[2*q]),     sv[2*q],     tv[2*q]);
            float x1 = fmaf(bf2f(a0[2*q + 1]), sv[2*q + 1], tv[2*q + 1]);
            x0 = fmaxf(x0, x0 * SLOPE);
            x1 = fmaxf(x1, x1 * SLOPE);
            p[q] = cvt_pk_bf16(x0, x1);
        }
        *(int4*)&As[buf][srow * 32 + scol] = make_int4(p[0], p[1], p[2], p[3]);
    };

    f32x4 acc[4][4];
#pragma unroll
    for (int i = 0; i < 4; ++i)
#pragma unroll
        for (int j = 0; j < 4; ++j) acc[i][j] = (f32x4){0.f, 0.f, 0.f, 0.f};

    const int frow = lane & 15;
    const int kg   = (lane >> 4) * 8;
    constexpr int nk = K / 32;

    {
        bf16x8 a0 = *(const bf16x8*)(A + arow + scol);
        stageB(0, 0);
        stA(0, 0, a0);
    }
    __syncthreads();

    for (int kk = 0; kk < nk; ++kk) {
        const int cur = kk & 1;
        const bool pre = (kk + 1 < nk);
        bf16x8 a0;
        if (pre) {
            const int k1 = (kk + 1) << 5;
            a0 = *(const bf16x8*)(A + arow + k1 + scol);
            stageB(cur ^ 1, k1);
        }

        bf16x8 af[4], bfr[4];
#pragma unroll
        for (int i = 0; i < 4; ++i)
            af[i] = *(const bf16x8*)&As[cur][(wm * 64 + i * 16 + frow) * 32 + kg];
#pragma unroll
        for (int j = 0; j < 4; ++j)
            bfr[j] = *(const bf16x8*)&Bs[cur][(wn * 64 + j * 16 + frow) * 32 + kg];
#pragma unroll
        for (int i = 0; i < 4; ++i)
#pragma unroll
            for (int j = 0; j < 4; ++j)
                acc[i][j] = __builtin_amdgcn_mfma_f32_16x16x32_bf16(
                    af[i], bfr[j], acc[i][j], 0, 0, 0);

        if (pre) stA(cur ^ 1, (kk + 1) << 5, a0);
        __syncthreads();
    }

    const int row_base = bm + wm * 64 + (lane >> 4) * 4;
    const int col_base = wn * 64 + (lane & 15);
#pragma unroll
    for (int i = 0; i < 4; ++i) {
#pragma unroll
        for (int r = 0; r < 4; ++r) {
            int row = row_base + i * 16 + r;
            if (row < M) {
                short* cp = C + (size_t)row * NC + col_base;
#pragma unroll
                for (int j = 0; j < 4; ++j) cp[j * 16] = f2bf(acc[i][j][r]);
            }
        }
    }
}

// ---------------------------------------------------------------------------
// GEMM with fused LN+leakyReLU on A, 128x128 block (layer 4, NC=128).
// grid.y == 1 for NC=128 so A is already read once. Validated in R4/R5.
// ---------------------------------------------------------------------------
__global__ __launch_bounds__(256)
void gemm_mfma_ln(const short* __restrict__ A, const short* __restrict__ Bt,
                  short* __restrict__ C, const float* __restrict__ st,
                  int M, int K, int NC) {
    __shared__ short As[2][128 * 32];
    __shared__ short Bs[2][128 * 32];
    const int tid  = threadIdx.x;
    const int lane = tid & 63;
    const int w    = tid >> 6;
    const int wm   = w & 1, wn = w >> 1;
    const int bm   = blockIdx.x * 128;
    const int bn   = blockIdx.y * 128;

    const int srow = w * 16 + (lane >> 2);
    const int scol = (lane & 3) * 8;

    const int ga_r0 = (bm + srow      < M) ? bm + srow      : M - 1;
    const int ga_r1 = (bm + srow + 64 < M) ? bm + srow + 64 : M - 1;
    const size_t arow0 = (size_t)ga_r0 * K;
    const size_t arow1 = (size_t)ga_r1 * K;
    const size_t brow0 = (size_t)(bn + srow) * K;
    const size_t brow1 = (size_t)(bn + srow + 64) * K;

    auto stageB = [&](int buf, int k0) {
        __builtin_amdgcn_global_load_lds(
            (const __attribute__((address_space(1))) void*)(Bt + brow0 + k0 + scol),
            (__attribute__((address_space(3))) void*)&Bs[buf][srow * 32 + scol], 16, 0, 0);
        __builtin_amdgcn_global_load_lds(
            (const __attribute__((address_space(1))) void*)(Bt + brow1 + k0 + scol),
            (__attribute__((address_space(3))) void*)&Bs[buf][(srow + 64) * 32 + scol], 16, 0, 0);
    };

    auto stA = [&](int buf, int k0, bf16x8 a0, bf16x8 a1) {
        const float* sp = st + k0 + scol;
        const float* tp = st + 256 + k0 + scol;
        float4 s0 = *(const float4*)sp,       s1 = *(const float4*)(sp + 4);
        float4 t0 = *(const float4*)tp,       t1 = *(const float4*)(tp + 4);
        float sv[8] = {s0.x, s0.y, s0.z, s0.w, s1.x, s1.y, s1.z, s1.w};
        float tv[8] = {t0.x, t0.y, t0.z, t0.w, t1.x, t1.y, t1.z, t1.w};
        unsigned p0[4], p1[4];
#pragma unroll
        for (int q = 0; q < 4; ++q) {
            float x0 = fmaf(bf2f(a0[2*q]),     sv[2*q],     tv[2*q]);
            float x1 = fmaf(bf2f(a0[2*q + 1]), sv[2*q + 1], tv[2*q + 1]);
            x0 = fmaxf(x0, x0 * SLOPE);
            x1 = fmaxf(x1, x1 * SLOPE);
            p0[q] = cvt_pk_bf16(x0, x1);
            float y0 = fmaf(bf2f(a1[2*q]),     sv[2*q],     tv[2*q]);
            float y1 = fmaf(bf2f(a1[2*q + 1]), sv[2*q + 1], tv[2*q + 1]);
            y0 = fmaxf(y0, y0 * SLOPE);
            y1 = fmaxf(y1, y1 * SLOPE);
            p1[q] = cvt_pk_bf16(y0, y1);
        }
        *(int4*)&As[buf][srow * 32 + scol]        = make_int4(p0[0], p0[1], p0[2], p0[3]);
        *(int4*)&As[buf][(srow + 64) * 32 + scol] = make_int4(p1[0], p1[1], p1[2], p1[3]);
    };

    f32x4 acc[4][4];
#pragma unroll
    for (int i = 0; i < 4; ++i)
#pragma unroll
        for (int j = 0; j < 4; ++j) acc[i][j] = (f32x4){0.f, 0.f, 0.f, 0.f};

    const int frow = lane & 15;
    const int kg   = (lane >> 4) * 8;
    const int nk   = K >> 5;

    {
        bf16x8 a0 = *(const bf16x8*)(A + arow0 + scol);
        bf16x8 a1 = *(const bf16x8*)(A + arow1 + scol);
        stageB(0, 0);
        stA(0, 0, a0, a1);
    }
    __syncthreads();

    for (int kk = 0; kk < nk; ++kk) {
        const int cur = kk & 1;
        const bool pre = (kk + 1 < nk);
        bf16x8 a0, a1;
        if (pre) {
            const int k1 = (kk + 1) << 5;
            a0 = *(const bf16x8*)(A + arow0 + k1 + scol);
            a1 = *(const bf16x8*)(A + arow1 + k1 + scol);
            stageB(cur ^ 1, k1);
        }

        bf16x8 af[4], bfr[4];
#pragma unroll
        for (int i = 0; i < 4; ++i)
            af[i] = *(const bf16x8*)&As[cur][(wm * 64 + i * 16 + frow) * 32 + kg];
#pragma unroll
        for (int j = 0; j < 4; ++j)
            bfr[j] = *(const bf16x8*)&Bs[cur][(wn * 64 + j * 16 + frow) * 32 + kg];
#pragma unroll
        for (int i = 0; i < 4; ++i)
#pragma unroll
            for (int j = 0; j < 4; ++j)
                acc[i][j] = __builtin_amdgcn_mfma_f32_16x16x32_bf16(
                    af[i], bfr[j], acc[i][j], 0, 0, 0);

        if (pre) stA(cur ^ 1, (kk + 1) << 5, a0, a1);
        __syncthreads();
    }

    const int row_base = bm + wm * 64 + (lane >> 4) * 4;
    const int col_base = bn + wn * 64 + (lane & 15);
#pragma unroll
    for (int i = 0; i < 4; ++i) {
#pragma unroll
        for (int r = 0; r < 4; ++r) {
            int row = row_base + i * 16 + r;
            if (row < M) {
                short* cp = C + (size_t)row * NC + col_base;
#pragma unroll
                for (int j = 0; j < 4; ++j) cp[j * 16] = f2bf(acc[i][j][r]);
            }
        }
    }
}

// ---------------------------------------------------------------------------
// CSR aggregation (bf16 gather, fp32 acc) + per-block LN partial stats.
// R1-proven: 4-deep unroll, contention-free psum/psumsq writes, NO fences,
// NO device-scope atomics.
// ---------------------------------------------------------------------------
__global__ __launch_bounds__(256)
void agg_ln_csr(const short* __restrict__ h, const int* __restrict__ rowptr,
                const int2* __restrict__ csr_iw, const float* __restrict__ dinv,
                const float* __restrict__ bias, short* __restrict__ agg,
                float* __restrict__ psum, float* __restrict__ psumsq, int N) {
    constexpr int TPN = 32;                 // D=256 bf16 -> 32 x 16B
    int t = blockIdx.x * 256 + threadIdx.x;
    int n = t / TPN, l = t % TPN;
    float acc[8] = {0.f, 0.f, 0.f, 0.f, 0.f, 0.f, 0.f, 0.f};
    if (n < N) {
        const bf16x8* h8 = (const bf16x8*)h;   // row = 32 vectors
        float di = dinv[n];
        float sl2 = di * di;
        bf16x8 sv = h8[(size_t)n * TPN + l];
        const float* bp = bias + l * 8;
#pragma unroll
        for (int c = 0; c < 8; ++c) acc[c] = bf2f(sv[c]) * sl2 + bp[c];
        int j = rowptr[n], j1 = rowptr[n + 1];
        for (; j + 3 < j1; j += 4) {
            int2 e0 = csr_iw[j],     e1 = csr_iw[j + 1];
            int2 e2 = csr_iw[j + 2], e3 = csr_iw[j + 3];
            float w0 = __int_as_float(e0.y), w1 = __int_as_float(e1.y);
            float w2 = __int_as_float(e2.y), w3 = __int_as_float(e3.y);
            bf16x8 v0 = h8[(size_t)e0.x * TPN + l];
            bf16x8 v1 = h8[(size_t)e1.x * TPN + l];
            bf16x8 v2 = h8[(size_t)e2.x * TPN + l];
            bf16x8 v3 = h8[(size_t)e3.x * TPN + l];
#pragma unroll
            for (int c = 0; c < 8; ++c)
                acc[c] += bf2f(v0[c]) * w0 + bf2f(v1[c]) * w1 +
                          bf2f(v2[c]) * w2 + bf2f(v3[c]) * w3;
        }
        if (j + 1 < j1) {
            int2 e0 = csr_iw[j], e1 = csr_iw[j + 1];
            float w0 = __int_as_float(e0.y), w1 = __int_as_float(e1.y);
            bf16x8 v0 = h8[(size_t)e0.x * TPN + l];
            bf16x8 v1 = h8[(size_t)e1.x * TPN + l];
#pragma unroll
            for (int c = 0; c < 8; ++c)
                acc[c] += bf2f(v0[c]) * w0 + bf2f(v1[c]) * w1;
            j += 2;
        }
        if (j < j1) {
            int2 e0 = csr_iw[j];
            float w0 = __int_as_float(e0.y);
            bf16x8 v0 = h8[(size_t)e0.x * TPN + l];
#pragma unroll
            for (int c = 0; c < 8; ++c) acc[c] += bf2f(v0[c]) * w0;
        }
        bf16x8 o;
#pragma unroll
        for (int c = 0; c < 8; ++c) o[c] = f2bf(acc[c]);
        ((bf16x8*)agg)[(size_t)n * TPN + l] = o;
    }
    // LN partial stats -> per-block array (contention-free)
    float s = 0.f, q = 0.f;
#pragma unroll
    for (int c = 0; c < 8; ++c) { s += acc[c]; q += acc[c] * acc[c]; }
#pragma unroll
    for (int off = 32; off; off >>= 1) {
        s += __shfl_down(s, off);
        q += __shfl_down(q, off);
    }
    __shared__ float ss[4], qq[4];
    int wid = threadIdx.x >> 6, lane = threadIdx.x & 63;
    if (lane == 0) { ss[wid] = s; qq[wid] = q; }
    __syncthreads();
    if (threadIdx.x == 0) {
        psum[blockIdx.x]   = ss[0] + ss[1] + ss[2] + ss[3];
        psumsq[blockIdx.x] = qq[0] + qq[1] + qq[2] + qq[3];
    }
}

// ---------------------------------------------------------------------------
// LN finalize: reduce per-block partials -> per-channel LN coefficients
// s[c]=inv*gamma[c], t[c]=beta[c]-mu*inv*gamma[c]
// ---------------------------------------------------------------------------
__global__ __launch_bounds__(1024)
void ln_finalize_st(const float* __restrict__ psum, const float* __restrict__ psumsq,
                    int nb, const float* __restrict__ gamma,
                    const float* __restrict__ beta, float* __restrict__ st, double M) {
    double s = 0.0, q = 0.0;
    for (int i = threadIdx.x; i < nb; i += 1024) {
        s += (double)psum[i];
        q += (double)psumsq[i];
    }
#pragma unroll
    for (int off = 32; off; off >>= 1) {
        s += __shfl_down(s, off);
        q += __shfl_down(q, off);
    }
    __shared__ double ss[16], qq[16];
    __shared__ float mi[2];
    int wid = threadIdx.x >> 6, lane = threadIdx.x & 63;
    if (lane == 0) { ss[wid] = s; qq[wid] = q; }
    __syncthreads();
    if (threadIdx.x == 0) {
        double S = 0.0, Q = 0.0;
        for (int i = 0; i < 16; ++i) { S += ss[i]; Q += qq[i]; }
        double mu  = S / M;
        double var = Q / M - mu * mu;
        if (var < 0.0) var = 0.0;
        mi[0] = (float)mu;
        mi[1] = 1.0f / ((float)sqrt(var) + EPS);
    }
    __syncthreads();
    if (threadIdx.x < 256) {
        int c = threadIdx.x;
        float mu = mi[0], inv = mi[1];
        float gv = gamma[c], bv = beta[c];
        st[c]       = inv * gv;
        st[256 + c] = bv - mu * inv * gv;
    }
}

// final layer: D=128, 16 lanes/node (16B), 4 nodes/wave, fp32 out, no stats
__global__ __launch_bounds__(256)
void agg_out_csr(const short* __restrict__ h, const int* __restrict__ rowptr,
                 const int2* __restrict__ csr_iw, const float* __restrict__ dinv,
                 const float* __restrict__ bias, float* __restrict__ out, int N) {
    constexpr int TPN = 16;                 // D=128 bf16 -> 16 x 16B
    int t = blockIdx.x * 256 + threadIdx.x;
    int n = t / TPN, l = t % TPN;
    if (n >= N) return;
    const bf16x8* h8 = (const bf16x8*)h;
    float di = dinv[n];
    float sl2 = di * di;
    bf16x8 sv = h8[(size_t)n * TPN + l];
    const float* bp = bias + l * 8;
    float acc[8];
#pragma unroll
    for (int c = 0; c < 8; ++c) acc[c] = bf2f(sv[c]) * sl2 + bp[c];
    int j = rowptr[n], j1 = rowptr[n + 1];
    for (; j + 3 < j1; j += 4) {
        int2 e0 = csr_iw[j],     e1 = csr_iw[j + 1];
        int2 e2 = csr_iw[j + 2], e3 = csr_iw[j + 3];
        float w0 = __int_as_float(e0.y), w1 = __int_as_float(e1.y);
        float w2 = __int_as_float(e2.y), w3 = __int_as_float(e3.y);
        bf16x8 v0 = h8[(size_t)e0.x * TPN + l];
        bf16x8 v1 = h8[(size_t)e1.x * TPN + l];
        bf16x8 v2 = h8[(size_t)e2.x * TPN + l];
        bf16x8 v3 = h8[(size_t)e3.x * TPN + l];
#pragma unroll
        for (int c = 0; c < 8; ++c)
            acc[c] += bf2f(v0[c]) * w0 + bf2f(v1[c]) * w1 +
                      bf2f(v2[c]) * w2 + bf2f(v3[c]) * w3;
    }
    if (j + 1 < j1) {
        int2 e0 = csr_iw[j], e1 = csr_iw[j + 1];
        float w0 = __int_as_float(e0.y), w1 = __int_as_float(e1.y);
        bf16x8 v0 = h8[(size_t)e0.x * TPN + l];
        bf16x8 v1 = h8[(size_t)e1.x * TPN + l];
#pragma unroll
        for (int c = 0; c < 8; ++c)
            acc[c] += bf2f(v0[c]) * w0 + bf2f(v1[c]) * w1;
        j += 2;
    }
    if (j < j1) {
        int2 e0 = csr_iw[j];
        float w0 = __int_as_float(e0.y);
        bf16x8 v0 = h8[(size_t)e0.x * TPN + l];
#pragma unroll
        for (int c = 0; c < 8; ++c) acc[c] += bf2f(v0[c]) * w0;
    }
    float4* op = (float4*)(out + (size_t)n * 128 + l * 8);
    op[0] = make_float4(acc[0], acc[1], acc[2], acc[3]);
    op[1] = make_float4(acc[4], acc[5], acc[6], acc[7]);
}

// ---------------------------------------------------------------------------
// launcher
// ---------------------------------------------------------------------------
extern "C" void kernel_launch(void* const* d_in, const int* in_sizes, int n_in,
                              void* d_out, int out_size, void* d_ws, size_t ws_size,
                              hipStream_t stream) {
    const float* x   = (const float*)d_in[0];
    const int*   ei  = (const int*)d_in[1];
    const float* W1  = (const float*)d_in[2];
    const float* b1  = (const float*)d_in[3];
    const float* g1  = (const float*)d_in[4];
    const float* be1 = (const float*)d_in[5];
    const float* W2  = (const float*)d_in[6];
    const float* b2  = (const float*)d_in[7];
    const float* g2  = (const float*)d_in[8];
    const float* be2 = (const float*)d_in[9];
    const float* W3  = (const float*)d_in[10];
    const float* b3  = (const float*)d_in[11];
    const float* g3  = (const float*)d_in[12];
    const float* be3 = (const float*)d_in[13];
    const float* W4  = (const float*)d_in[14];
    const float* b4  = (const float*)d_in[15];

    const int N = in_sizes[0] / DH;   // 100000
    const int E = in_sizes[1] / 2;    // 800000
    const int* src = ei;
    const int* dst = ei + E;
    const int nb = (N + 1023) / 1024;
    const int nagg = (N * 32 + 255) / 256;   // agg_ln_csr blocks (12500)

    char* w = (char*)d_ws;
    size_t off = 0;
    auto alloc = [&](size_t bytes) { char* p = w + off; off = (off + bytes + 255) & ~(size_t)255; return p; };
    int*    deg      = (int*)alloc((size_t)N * 4);
    int*    fill     = (int*)alloc((size_t)N * 4);
    int*    rowptr   = (int*)alloc((size_t)(N + 1) * 4);
    int*    blocksum = (int*)alloc(256 * 4);
    int*    blockoff = (int*)alloc(256 * 4);
    float*  dinv     = (float*)alloc((size_t)N * 4);
    float*  psum     = (float*)alloc((size_t)nagg * 4);
    float*  psumsq   = (float*)alloc((size_t)nagg * 4);
    float*  st1      = (float*)alloc(512 * 4);
    float*  st2      = (float*)alloc(512 * 4);
    float*  st3      = (float*)alloc(512 * 4);
    int2*   csr_iw   = (int2*)alloc((size_t)E * 8);
    short*  Wt1      = (short*)alloc((size_t)DH * DH * 2);
    short*  Wt2      = (short*)alloc((size_t)DH * DH * 2);
    short*  Wt3      = (short*)alloc((size_t)DH * DH * 2);
    short*  Wt4      = (short*)alloc((size_t)DZ * DH * 2);
    short*  hbf      = (short*)alloc((size_t)N * DH * 2);
    short*  aggb     = (short*)alloc((size_t)N * DH * 2);

    // ---- one memset for deg + fill (contiguous) ----
    hipMemsetAsync(deg, 0, (size_t)((char*)rowptr - (char*)deg), stream);

    // ---- degree, dinv, CSR build ----
    deg_count_i<<<(E + 255) / 256, 256, 0, stream>>>(dst, deg, E);
    make_dinv<<<(N + 255) / 256, 256, 0, stream>>>(deg, dinv, N);
    scan1<<<nb, 256, 0, stream>>>(deg, rowptr, blocksum, N);
    scan2<<<1, 256, 0, stream>>>(blocksum, blockoff, nb, rowptr + N);
    scan3<<<(N + 255) / 256, 256, 0, stream>>>(rowptr, blockoff, N);
    csr_fill<<<(E + 255) / 256, 256, 0, stream>>>(src, dst, rowptr, fill, csr_iw, dinv, E);

    // ---- weight transpose+cast ----
    wt_cast<<<(DH * DH + 255) / 256, 256, 0, stream>>>(W1, Wt1, DH, DH);
    wt_cast<<<(DH * DH + 255) / 256, 256, 0, stream>>>(W2, Wt2, DH, DH);
    wt_cast<<<(DH * DH + 255) / 256, 256, 0, stream>>>(W3, Wt3, DH, DH);
    wt_cast<<<(DH * DZ + 255) / 256, 256, 0, stream>>>(W4, Wt4, DH, DZ);

    const int gmM = (N + 127) / 128;
    const double M = (double)N * (double)DH;

    // layer 1: wide gemm with fused f32->bf16 cast on A (reads x directly)
    gemm_cast_w<<<gmM, 512, 0, stream>>>(x, Wt1, hbf, N);
    agg_ln_csr<<<nagg, 256, 0, stream>>>(hbf, rowptr, csr_iw, dinv, b1, aggb,
                                         psum, psumsq, N);
    ln_finalize_st<<<1, 1024, 0, stream>>>(psum, psumsq, nagg, g1, be1, st1, M);
    // layer 2: wide gemm, LN1+leaky fused into A-staging
    gemm_ln_w<<<gmM, 512, 0, stream>>>(aggb, Wt2, hbf, st1, N);
    agg_ln_csr<<<nagg, 256, 0, stream>>>(hbf, rowptr, csr_iw, dinv, b2, aggb,
                                         psum, psumsq, N);
    ln_finalize_st<<<1, 1024, 0, stream>>>(psum, psumsq, nagg, g2, be2, st2, M);
    // layer 3
    gemm_ln_w<<<gmM, 512, 0, stream>>>(aggb, Wt3, hbf, st2, N);
    agg_ln_csr<<<nagg, 256, 0, stream>>>(hbf, rowptr, csr_iw, dinv, b3, aggb,
                                         psum, psumsq, N);
    ln_finalize_st<<<1, 1024, 0, stream>>>(psum, psumsq, nagg, g3, be3, st3, M);
    // final conv: LN3+leaky fused, DH -> DZ (NC=128, grid.y=1 already)
    gemm_mfma_ln<<<dim3(gmM, DZ / 128), 256, 0, stream>>>(aggb, Wt4, hbf, st3, N, DH, DZ);
    float* out = (float*)d_out;
    int naggz = (N * 16 + 255) / 256;
    agg_out_csr<<<naggz, 256, 0, stream>>>(hbf, rowptr, csr_iw, dinv, b4, out, N);
}